// Round 1
// baseline (5859.298 us; speedup 1.0000x reference)
//
#include <hip/hip_runtime.h>
#include <hip/hip_bf16.h>
#include <math.h>

#define NNODES 50000
#define NEDGES 800000
#define NHOPS  4
#define NF     256
#define NH     128
#define NO     64

// ---------------------------------------------------------------------------
// Linear: h[m][j] = sum_f x[m][f] * Wk[f][j] + bk[j]
// Tile: BM=64, BN=128, BK=32. 256 threads as 16x16, each computes 4 rows x 8 cols
// (cols split tx*4 and 64+tx*4 so LDS reads are <=2-way bank aliased = free).
// ---------------------------------------------------------------------------
__global__ __launch_bounds__(256) void linear_kernel(
    const float* __restrict__ x, const float* __restrict__ Wk,
    const float* __restrict__ bk, float* __restrict__ h) {
  __shared__ float xs[32 * 64];    // [f][m] (transposed so m contiguous)
  __shared__ float ws[32 * 128];   // [f][n]
  const int t  = threadIdx.x;
  const int tx = t & 15;           // col group
  const int ty = t >> 4;           // row group
  const int m0 = blockIdx.x * 64;

  float acc[4][8];
#pragma unroll
  for (int i = 0; i < 4; ++i)
#pragma unroll
    for (int j = 0; j < 8; ++j) acc[i][j] = 0.f;

  for (int f0 = 0; f0 < NF; f0 += 32) {
    // --- load x tile (64 rows x 32 f), store transposed into xs[f][m] ---
    {
      const int lrow = t >> 2;          // 0..63
      const int lf   = (t & 3) * 8;     // 0,8,16,24
      const int grow = m0 + lrow;
      float4 a0 = make_float4(0.f, 0.f, 0.f, 0.f);
      float4 a1 = make_float4(0.f, 0.f, 0.f, 0.f);
      if (grow < NNODES) {
        a0 = *(const float4*)&x[(size_t)grow * NF + f0 + lf];
        a1 = *(const float4*)&x[(size_t)grow * NF + f0 + lf + 4];
      }
      xs[(lf + 0) * 64 + lrow] = a0.x;
      xs[(lf + 1) * 64 + lrow] = a0.y;
      xs[(lf + 2) * 64 + lrow] = a0.z;
      xs[(lf + 3) * 64 + lrow] = a0.w;
      xs[(lf + 4) * 64 + lrow] = a1.x;
      xs[(lf + 5) * 64 + lrow] = a1.y;
      xs[(lf + 6) * 64 + lrow] = a1.z;
      xs[(lf + 7) * 64 + lrow] = a1.w;
    }
    // --- load W tile (32 f x 128 n) straight copy ---
    {
      const int nq = (t & 31) * 4;
#pragma unroll
      for (int s = 0; s < 4; ++s) {
        const int ff = (t >> 5) + 8 * s;   // 0..31
        float4 w = *(const float4*)&Wk[(size_t)(f0 + ff) * NH + nq];
        *(float4*)&ws[ff * NH + nq] = w;
      }
    }
    __syncthreads();

#pragma unroll
    for (int f = 0; f < 32; ++f) {
      float4 a  = *(float4*)&xs[f * 64 + ty * 4];
      float4 b0 = *(float4*)&ws[f * NH + tx * 4];
      float4 b1 = *(float4*)&ws[f * NH + 64 + tx * 4];
      float av[4] = {a.x, a.y, a.z, a.w};
      float bv[8] = {b0.x, b0.y, b0.z, b0.w, b1.x, b1.y, b1.z, b1.w};
#pragma unroll
      for (int i = 0; i < 4; ++i)
#pragma unroll
        for (int j = 0; j < 8; ++j) acc[i][j] += av[i] * bv[j];
    }
    __syncthreads();
  }

  // --- epilogue: add bias, store ---
  float bb[8];
#pragma unroll
  for (int u = 0; u < 4; ++u) {
    bb[u]     = bk[tx * 4 + u];
    bb[4 + u] = bk[64 + tx * 4 + u];
  }
#pragma unroll
  for (int i = 0; i < 4; ++i) {
    const int row = m0 + ty * 4 + i;
    if (row < NNODES) {
      float4 o0 = make_float4(acc[i][0] + bb[0], acc[i][1] + bb[1],
                              acc[i][2] + bb[2], acc[i][3] + bb[3]);
      float4 o1 = make_float4(acc[i][4] + bb[4], acc[i][5] + bb[5],
                              acc[i][6] + bb[6], acc[i][7] + bb[7]);
      *(float4*)&h[(size_t)row * NH + tx * 4]      = o0;
      *(float4*)&h[(size_t)row * NH + 64 + tx * 4] = o1;
    }
  }
}

// ---------------------------------------------------------------------------
// SpMM (COO, atomic scatter): agg[r][j] += val * h[c][j]
// Block = 256 threads = 8 edges x 32 lanes x 4 feats (float4 gather).
// ---------------------------------------------------------------------------
__global__ __launch_bounds__(256) void spmm_kernel(
    const int* __restrict__ rows, const int* __restrict__ cols,
    const float* __restrict__ vals, const float* __restrict__ h,
    float* __restrict__ aggk) {
  const int t = threadIdx.x;
  const int e = blockIdx.x * 8 + (t >> 5);
  if (e >= NEDGES) return;
  const int   r = rows[e];
  const int   c = cols[e];
  const float v = vals[e];
  const int   j = (t & 31) * 4;
  const float4 hv = *(const float4*)&h[(size_t)c * NH + j];
  float* dst = &aggk[(size_t)r * NH + j];
  atomicAdd(dst + 0, v * hv.x);
  atomicAdd(dst + 1, v * hv.y);
  atomicAdd(dst + 2, v * hv.z);
  atomicAdd(dst + 3, v * hv.w);
}

// ---------------------------------------------------------------------------
// Output: out[n][o] = b_out[o] + sum_f elu(concat[n][f]) * W_out[f][o]
// concat[n][k*128+j] = agg[k][n][j]. Block = 64 threads, 16 nodes.
// zs row stride 516 (=512+4) to break bank conflicts on the 512 stride.
// Thread (og=t&15, ng=t>>4) computes 4 nodes x 4 outs.
// ---------------------------------------------------------------------------
__global__ __launch_bounds__(64) void out_kernel(
    const float* __restrict__ agg, const float* __restrict__ Wout,
    const float* __restrict__ bout, float* __restrict__ out) {
  __shared__ float zs[16 * 516];
  const int t  = threadIdx.x;   // 0..63
  const int n0 = blockIdx.x * 16;

  // stage 16 nodes x 512 feats with ELU applied
#pragma unroll
  for (int cch = 0; cch < 32; ++cch) {
    const int flat = cch * 256 + t * 4;     // 0..8188, step 4
    const int n_l  = flat >> 9;             // 0..15
    const int f    = flat & 511;            // multiple of 4
    const int k    = f >> 7;
    const int j    = f & 127;
    float4 v = *(const float4*)&agg[((size_t)k * NNODES + n0 + n_l) * NH + j];
    v.x = v.x > 0.f ? v.x : (expf(v.x) - 1.f);
    v.y = v.y > 0.f ? v.y : (expf(v.y) - 1.f);
    v.z = v.z > 0.f ? v.z : (expf(v.z) - 1.f);
    v.w = v.w > 0.f ? v.w : (expf(v.w) - 1.f);
    *(float4*)&zs[n_l * 516 + f] = v;
  }
  __syncthreads();

  const int og = t & 15;   // out group: o = og*4..og*4+3
  const int ng = t >> 4;   // node group: n = ng*4..ng*4+3
  float acc[4][4];
#pragma unroll
  for (int i = 0; i < 4; ++i)
#pragma unroll
    for (int o = 0; o < 4; ++o) acc[i][o] = 0.f;

  for (int fq = 0; fq < 128; ++fq) {
    const int f = fq * 4;
    float4 z[4], w[4];
#pragma unroll
    for (int i = 0; i < 4; ++i)
      z[i] = *(float4*)&zs[(ng * 4 + i) * 516 + f];
#pragma unroll
    for (int u = 0; u < 4; ++u)
      w[u] = *(const float4*)&Wout[(size_t)(f + u) * NO + og * 4];
    float zv[4][4] = {{z[0].x, z[0].y, z[0].z, z[0].w},
                      {z[1].x, z[1].y, z[1].z, z[1].w},
                      {z[2].x, z[2].y, z[2].z, z[2].w},
                      {z[3].x, z[3].y, z[3].z, z[3].w}};
    float wv[4][4] = {{w[0].x, w[0].y, w[0].z, w[0].w},
                      {w[1].x, w[1].y, w[1].z, w[1].w},
                      {w[2].x, w[2].y, w[2].z, w[2].w},
                      {w[3].x, w[3].y, w[3].z, w[3].w}};
#pragma unroll
    for (int i = 0; i < 4; ++i)
#pragma unroll
      for (int u = 0; u < 4; ++u)
#pragma unroll
        for (int o = 0; o < 4; ++o) acc[i][o] += zv[i][u] * wv[u][o];
  }

  float bo[4];
#pragma unroll
  for (int o = 0; o < 4; ++o) bo[o] = bout[og * 4 + o];
#pragma unroll
  for (int i = 0; i < 4; ++i) {
    const int n = n0 + ng * 4 + i;
    float4 r = make_float4(acc[i][0] + bo[0], acc[i][1] + bo[1],
                           acc[i][2] + bo[2], acc[i][3] + bo[3]);
    *(float4*)&out[(size_t)n * NO + og * 4] = r;
  }
}

// ---------------------------------------------------------------------------
extern "C" void kernel_launch(void* const* d_in, const int* in_sizes, int n_in,
                              void* d_out, int out_size, void* d_ws, size_t ws_size,
                              hipStream_t stream) {
  const float* x     = (const float*)d_in[0];
  const float* W     = (const float*)d_in[1];
  const float* b     = (const float*)d_in[2];
  const float* W_out = (const float*)d_in[3];
  const float* b_out = (const float*)d_in[4];
  const int*   erows = (const int*)d_in[5];
  const int*   ecols = (const int*)d_in[6];
  const float* evals = (const float*)d_in[7];
  float* out = (float*)d_out;

  float* agg   = (float*)d_ws;                               // 4*50000*128 floats
  float* h_tmp = agg + (size_t)NHOPS * NNODES * NH;          // 50000*128 floats

  hipMemsetAsync(agg, 0, (size_t)NHOPS * NNODES * NH * sizeof(float), stream);

  const int lin_blocks  = (NNODES + 63) / 64;        // 782
  const int spmm_blocks = NEDGES / 8;                // 100000

  for (int k = 0; k < NHOPS; ++k) {
    linear_kernel<<<lin_blocks, 256, 0, stream>>>(
        x, W + (size_t)k * NF * NH, b + (size_t)k * NH, h_tmp);
    spmm_kernel<<<spmm_blocks, 256, 0, stream>>>(
        erows + (size_t)k * NEDGES, ecols + (size_t)k * NEDGES,
        evals + (size_t)k * NEDGES, h_tmp,
        agg + (size_t)k * NNODES * NH);
  }

  out_kernel<<<NNODES / 16, 64, 0, stream>>>(agg, W_out, b_out, out);
}

// Round 2
// 1088.716 us; speedup vs baseline: 5.3818x; 5.3818x over previous
//
#include <hip/hip_runtime.h>
#include <hip/hip_bf16.h>
#include <math.h>

#define NNODES 50000
#define NEDGES 800000
#define NHOPS  4
#define NF     256
#define NH     128
#define NO     64

static __device__ __forceinline__ unsigned short f2bf(float f) {
  unsigned int u = __float_as_uint(f);
  unsigned int r = (u + 0x7fffu + ((u >> 16) & 1u)) >> 16;
  return (unsigned short)r;
}
static __device__ __forceinline__ float bf2f_lo(unsigned int u) {
  return __uint_as_float(u << 16);
}
static __device__ __forceinline__ float bf2f_hi(unsigned int u) {
  return __uint_as_float(u & 0xffff0000u);
}

// ---------------------------------------------------------------------------
// Linear: h[m][j] = sum_f x[m][f] * Wk[f][j] + bk[j]   (f32, VALU)
// BM=64, BN=128, BK=32. 256 threads as 16x16, each 4 rows x 8 cols.
// ---------------------------------------------------------------------------
__global__ __launch_bounds__(256) void linear_kernel(
    const float* __restrict__ x, const float* __restrict__ Wk,
    const float* __restrict__ bk, float* __restrict__ h) {
  __shared__ float xs[32 * 64];    // [f][m]
  __shared__ float ws[32 * 128];   // [f][n]
  const int t  = threadIdx.x;
  const int tx = t & 15;
  const int ty = t >> 4;
  const int m0 = blockIdx.x * 64;

  float acc[4][8];
#pragma unroll
  for (int i = 0; i < 4; ++i)
#pragma unroll
    for (int j = 0; j < 8; ++j) acc[i][j] = 0.f;

  for (int f0 = 0; f0 < NF; f0 += 32) {
    {
      const int lrow = t >> 2;
      const int lf   = (t & 3) * 8;
      const int grow = m0 + lrow;
      float4 a0 = make_float4(0.f, 0.f, 0.f, 0.f);
      float4 a1 = make_float4(0.f, 0.f, 0.f, 0.f);
      if (grow < NNODES) {
        a0 = *(const float4*)&x[(size_t)grow * NF + f0 + lf];
        a1 = *(const float4*)&x[(size_t)grow * NF + f0 + lf + 4];
      }
      xs[(lf + 0) * 64 + lrow] = a0.x;
      xs[(lf + 1) * 64 + lrow] = a0.y;
      xs[(lf + 2) * 64 + lrow] = a0.z;
      xs[(lf + 3) * 64 + lrow] = a0.w;
      xs[(lf + 4) * 64 + lrow] = a1.x;
      xs[(lf + 5) * 64 + lrow] = a1.y;
      xs[(lf + 6) * 64 + lrow] = a1.z;
      xs[(lf + 7) * 64 + lrow] = a1.w;
    }
    {
      const int nq = (t & 31) * 4;
#pragma unroll
      for (int s = 0; s < 4; ++s) {
        const int ff = (t >> 5) + 8 * s;
        float4 w = *(const float4*)&Wk[(size_t)(f0 + ff) * NH + nq];
        *(float4*)&ws[ff * NH + nq] = w;
      }
    }
    __syncthreads();

#pragma unroll
    for (int f = 0; f < 32; ++f) {
      float4 a  = *(float4*)&xs[f * 64 + ty * 4];
      float4 b0 = *(float4*)&ws[f * NH + tx * 4];
      float4 b1 = *(float4*)&ws[f * NH + 64 + tx * 4];
      float av[4] = {a.x, a.y, a.z, a.w};
      float bv[8] = {b0.x, b0.y, b0.z, b0.w, b1.x, b1.y, b1.z, b1.w};
#pragma unroll
      for (int i = 0; i < 4; ++i)
#pragma unroll
        for (int j = 0; j < 8; ++j) acc[i][j] += av[i] * bv[j];
    }
    __syncthreads();
  }

  float bb[8];
#pragma unroll
  for (int u = 0; u < 4; ++u) {
    bb[u]     = bk[tx * 4 + u];
    bb[4 + u] = bk[64 + tx * 4 + u];
  }
#pragma unroll
  for (int i = 0; i < 4; ++i) {
    const int row = m0 + ty * 4 + i;
    if (row < NNODES) {
      float4 o0 = make_float4(acc[i][0] + bb[0], acc[i][1] + bb[1],
                              acc[i][2] + bb[2], acc[i][3] + bb[3]);
      float4 o1 = make_float4(acc[i][4] + bb[4], acc[i][5] + bb[5],
                              acc[i][6] + bb[6], acc[i][7] + bb[7]);
      *(float4*)&h[(size_t)row * NH + tx * 4]      = o0;
      *(float4*)&h[(size_t)row * NH + 64 + tx * 4] = o1;
    }
  }
}

// ---------------------------------------------------------------------------
// CSR build step 1: histogram of row ids. counts[hop][r]++
// ---------------------------------------------------------------------------
__global__ __launch_bounds__(256) void hist_kernel(
    const int* __restrict__ rows, int* __restrict__ counts) {
  const int hop = blockIdx.y;
  const int e = blockIdx.x * 256 + threadIdx.x;
  if (e >= NEDGES) return;
  const int r = rows[(size_t)hop * NEDGES + e];
  atomicAdd(&counts[hop * NNODES + r], 1);
}

// ---------------------------------------------------------------------------
// CSR build step 2: exclusive scan per hop (1 block of 1024 per hop).
// Writes offs[hop][0..N] and cursor[hop][0..N-1] (= copy of offs).
// ---------------------------------------------------------------------------
__global__ __launch_bounds__(1024) void scan_kernel(
    const int* __restrict__ counts, int* __restrict__ offs,
    int* __restrict__ cursor) {
  const int hop  = blockIdx.x;
  const int t    = threadIdx.x;
  const int lane = t & 63;
  const int wid  = t >> 6;          // 0..15
  __shared__ int wsum[16];
  __shared__ int carry_s;
  if (t == 0) carry_s = 0;
  __syncthreads();
  const int nch = (NNODES + 1023) / 1024;   // 49
  for (int ch = 0; ch < nch; ++ch) {
    const int i = ch * 1024 + t;
    int v = (i < NNODES) ? counts[hop * NNODES + i] : 0;
    int s = v;
#pragma unroll
    for (int d = 1; d < 64; d <<= 1) {
      int n = __shfl_up(s, d, 64);
      if (lane >= d) s += n;
    }
    if (lane == 63) wsum[wid] = s;
    __syncthreads();
    if (t < 16) {
      int ws = wsum[t];
#pragma unroll
      for (int d = 1; d < 16; d <<= 1) {
        int n = __shfl_up(ws, d, 16);
        if (t >= d) ws += n;
      }
      wsum[t] = ws;
    }
    __syncthreads();
    const int base = carry_s + (wid ? wsum[wid - 1] : 0);
    const int excl = base + (s - v);
    if (i < NNODES) {
      offs[hop * (NNODES + 1) + i] = excl;
      cursor[hop * NNODES + i]     = excl;
    }
    __syncthreads();
    if (t == 0) carry_s += wsum[15];
    __syncthreads();
  }
  if (t == 0) offs[hop * (NNODES + 1) + NNODES] = carry_s;
}

// ---------------------------------------------------------------------------
// CSR build step 3: scatter edges into csr order.
// ---------------------------------------------------------------------------
__global__ __launch_bounds__(256) void scatter_kernel(
    const int* __restrict__ rows, const int* __restrict__ cols,
    const float* __restrict__ vals, int* __restrict__ cursor,
    int* __restrict__ ccol, float* __restrict__ cval) {
  const int hop = blockIdx.y;
  const int e = blockIdx.x * 256 + threadIdx.x;
  if (e >= NEDGES) return;
  const size_t g = (size_t)hop * NEDGES + e;
  const int r = rows[g];
  const int pos = atomicAdd(&cursor[hop * NNODES + r], 1);
  ccol[(size_t)hop * NEDGES + pos] = cols[g];
  cval[(size_t)hop * NEDGES + pos] = vals[g];
}

// ---------------------------------------------------------------------------
// Gather SpMM: agg[r][:] = sum over csr segment of val * h[col][:]
// 1 wave per row, float2 per lane; no atomics; writes bf16.
// ---------------------------------------------------------------------------
__global__ __launch_bounds__(256) void gather_kernel(
    const int* __restrict__ offs, const int* __restrict__ ccol,
    const float* __restrict__ cval, const float* __restrict__ h,
    unsigned short* __restrict__ aggb) {
  const int t    = threadIdx.x;
  const int lane = t & 63;
  const int wid  = t >> 6;
  const int r = blockIdx.x * 4 + wid;
  if (r >= NNODES) return;
  const int s = offs[r];
  const int e = offs[r + 1];
  const float2* h2 = (const float2*)h;
  float2 acc = make_float2(0.f, 0.f);
  int p = s;
  for (; p + 1 < e; p += 2) {
    const int   c0 = ccol[p];
    const int   c1 = ccol[p + 1];
    const float v0 = cval[p];
    const float v1 = cval[p + 1];
    const float2 a = h2[(size_t)c0 * 64 + lane];
    const float2 b = h2[(size_t)c1 * 64 + lane];
    acc.x += v0 * a.x + v1 * b.x;
    acc.y += v0 * a.y + v1 * b.y;
  }
  if (p < e) {
    const int   c0 = ccol[p];
    const float v0 = cval[p];
    const float2 a = h2[(size_t)c0 * 64 + lane];
    acc.x += v0 * a.x;
    acc.y += v0 * a.y;
  }
  ushort2 o;
  o.x = f2bf(acc.x);
  o.y = f2bf(acc.y);
  *(ushort2*)&aggb[(size_t)r * NH + lane * 2] = o;
}

// ---------------------------------------------------------------------------
// Output: out[n][o] = b_out[o] + sum_f elu(concat[n][f]) * W_out[f][o]
// concat[n][k*128+j] = agg[k][n][j] (bf16). 64 threads, 16 nodes/block.
// ---------------------------------------------------------------------------
__global__ __launch_bounds__(64) void out_kernel(
    const unsigned short* __restrict__ aggb, const float* __restrict__ Wout,
    const float* __restrict__ bout, float* __restrict__ out) {
  __shared__ float zs[16 * 516];
  const int t  = threadIdx.x;
  const int n0 = blockIdx.x * 16;

#pragma unroll
  for (int cch = 0; cch < 32; ++cch) {
    const int flat = cch * 256 + t * 4;
    const int n_l  = flat >> 9;
    const int f    = flat & 511;
    const int k    = f >> 7;
    const int j    = f & 127;
    const uint2 u = *(const uint2*)&aggb[((size_t)k * NNODES + n0 + n_l) * NH + j];
    float4 v = make_float4(bf2f_lo(u.x), bf2f_hi(u.x), bf2f_lo(u.y), bf2f_hi(u.y));
    v.x = v.x > 0.f ? v.x : (expf(v.x) - 1.f);
    v.y = v.y > 0.f ? v.y : (expf(v.y) - 1.f);
    v.z = v.z > 0.f ? v.z : (expf(v.z) - 1.f);
    v.w = v.w > 0.f ? v.w : (expf(v.w) - 1.f);
    *(float4*)&zs[n_l * 516 + f] = v;
  }
  __syncthreads();

  const int og = t & 15;
  const int ng = t >> 4;
  float acc[4][4];
#pragma unroll
  for (int i = 0; i < 4; ++i)
#pragma unroll
    for (int o = 0; o < 4; ++o) acc[i][o] = 0.f;

  for (int fq = 0; fq < 128; ++fq) {
    const int f = fq * 4;
    float4 z[4], w[4];
#pragma unroll
    for (int i = 0; i < 4; ++i)
      z[i] = *(float4*)&zs[(ng * 4 + i) * 516 + f];
#pragma unroll
    for (int u = 0; u < 4; ++u)
      w[u] = *(const float4*)&Wout[(size_t)(f + u) * NO + og * 4];
    float zv[4][4] = {{z[0].x, z[0].y, z[0].z, z[0].w},
                      {z[1].x, z[1].y, z[1].z, z[1].w},
                      {z[2].x, z[2].y, z[2].z, z[2].w},
                      {z[3].x, z[3].y, z[3].z, z[3].w}};
    float wv[4][4] = {{w[0].x, w[0].y, w[0].z, w[0].w},
                      {w[1].x, w[1].y, w[1].z, w[1].w},
                      {w[2].x, w[2].y, w[2].z, w[2].w},
                      {w[3].x, w[3].y, w[3].z, w[3].w}};
#pragma unroll
    for (int i = 0; i < 4; ++i)
#pragma unroll
      for (int u = 0; u < 4; ++u)
#pragma unroll
        for (int o = 0; o < 4; ++o) acc[i][o] += zv[i][u] * wv[u][o];
  }

  float bo[4];
#pragma unroll
  for (int o = 0; o < 4; ++o) bo[o] = bout[og * 4 + o];
#pragma unroll
  for (int i = 0; i < 4; ++i) {
    const int n = n0 + ng * 4 + i;
    float4 r = make_float4(acc[i][0] + bo[0], acc[i][1] + bo[1],
                           acc[i][2] + bo[2], acc[i][3] + bo[3]);
    *(float4*)&out[(size_t)n * NO + og * 4] = r;
  }
}

// ---------------------------------------------------------------------------
extern "C" void kernel_launch(void* const* d_in, const int* in_sizes, int n_in,
                              void* d_out, int out_size, void* d_ws, size_t ws_size,
                              hipStream_t stream) {
  const float* x     = (const float*)d_in[0];
  const float* W     = (const float*)d_in[1];
  const float* b     = (const float*)d_in[2];
  const float* W_out = (const float*)d_in[3];
  const float* b_out = (const float*)d_in[4];
  const int*   erows = (const int*)d_in[5];
  const int*   ecols = (const int*)d_in[6];
  const float* evals = (const float*)d_in[7];
  float* out = (float*)d_out;

  // workspace layout (bytes): total ~104.8e6 < 128e6 known-safe
  unsigned short* aggb = (unsigned short*)d_ws;                 // 4*50000*128*2 = 51.2e6
  float* h_tmp = (float*)(aggb + (size_t)NHOPS * NNODES * NH);  // 25.6e6
  int*   ccol  = (int*)(h_tmp + (size_t)NNODES * NH);           // 12.8e6
  float* cval  = (float*)(ccol + (size_t)NHOPS * NEDGES);       // 12.8e6
  int*   counts = (int*)(cval + (size_t)NHOPS * NEDGES);        // 0.8e6
  int*   offs   = counts + NHOPS * NNODES;                      // ~0.8e6
  int*   cursor = offs + NHOPS * (NNODES + 1);                  // 0.8e6

  hipMemsetAsync(counts, 0, (size_t)NHOPS * NNODES * sizeof(int), stream);

  const dim3 egrid((NEDGES + 255) / 256, NHOPS);
  hist_kernel<<<egrid, 256, 0, stream>>>(erows, counts);
  scan_kernel<<<NHOPS, 1024, 0, stream>>>(counts, offs, cursor);
  scatter_kernel<<<egrid, 256, 0, stream>>>(erows, ecols, evals, cursor, ccol, cval);

  const int lin_blocks = (NNODES + 63) / 64;   // 782
  for (int k = 0; k < NHOPS; ++k) {
    linear_kernel<<<lin_blocks, 256, 0, stream>>>(
        x, W + (size_t)k * NF * NH, b + (size_t)k * NH, h_tmp);
    gather_kernel<<<(NNODES + 3) / 4, 256, 0, stream>>>(
        offs + (size_t)k * (NNODES + 1), ccol + (size_t)k * NEDGES,
        cval + (size_t)k * NEDGES, h_tmp, aggb + (size_t)k * NNODES * NH);
  }

  out_kernel<<<NNODES / 16, 64, 0, stream>>>(aggb, W_out, b_out, out);
}

// Round 3
// 948.087 us; speedup vs baseline: 6.1801x; 1.1483x over previous
//
#include <hip/hip_runtime.h>
#include <hip/hip_bf16.h>
#include <math.h>

#define NNODES 50000
#define NPAD   50176              // 392*128, padded rows for MFMA tile overrun
#define NEDGES 800000
#define NHOPS  4
#define NF     256
#define NH     128
#define NO     64

typedef __attribute__((ext_vector_type(8))) short bfrag_t;   // 8 x bf16
typedef __attribute__((ext_vector_type(4))) float facc_t;    // 4 x f32

static __device__ __forceinline__ unsigned short f2bf(float f) {
  unsigned int u = __float_as_uint(f);
  unsigned int r = (u + 0x7fffu + ((u >> 16) & 1u)) >> 16;
  return (unsigned short)r;
}
static __device__ __forceinline__ float bf2f_lo(unsigned int u) {
  return __uint_as_float(u << 16);
}
static __device__ __forceinline__ float bf2f_hi(unsigned int u) {
  return __uint_as_float(u & 0xffff0000u);
}

// ---------------------------------------------------------------------------
// Convert x (f32) -> xb (bf16), rows [0,NNODES). Pad rows stay poison (masked
// at the linear epilogue, garbage cannot leak into valid output rows).
// ---------------------------------------------------------------------------
__global__ __launch_bounds__(256) void convx_kernel(
    const float* __restrict__ x, unsigned short* __restrict__ xb) {
  const size_t i = ((size_t)blockIdx.x * 256 + threadIdx.x) * 4;
  if (i >= (size_t)NNODES * NF) return;
  float4 v = *(const float4*)&x[i];
  ushort4 o;
  o.x = f2bf(v.x); o.y = f2bf(v.y); o.z = f2bf(v.z); o.w = f2bf(v.w);
  *(ushort4*)&xb[i] = o;
}

// ---------------------------------------------------------------------------
// Convert W [k][f][n] (f32) -> Wt [k][n][f] (bf16). Tiny (131072 elems).
// ---------------------------------------------------------------------------
__global__ __launch_bounds__(256) void convw_kernel(
    const float* __restrict__ W, unsigned short* __restrict__ Wt) {
  const int i = blockIdx.x * 256 + threadIdx.x;
  if (i >= NHOPS * NH * NF) return;
  const int k = i / (NH * NF);
  const int rem = i - k * NH * NF;
  const int n = rem / NF;
  const int f = rem - n * NF;
  Wt[i] = f2bf(W[(size_t)k * NF * NH + (size_t)f * NH + n]);
}

// ---------------------------------------------------------------------------
// Linear via MFMA: hb[m][n] = bf16( sum_k xb[m][k]*Wt[n][k] + bk[n] )
// Block = 256 thr = 4 waves (2x2), each wave 64x64 via 4x4 16x16x32 tiles.
// No LDS: A/B fragments are 16B-contiguous loads, W reuse hits L1/L2.
// ---------------------------------------------------------------------------
__global__ __launch_bounds__(256) void linear_mfma(
    const unsigned short* __restrict__ xb, const unsigned short* __restrict__ Wt,
    const float* __restrict__ bk, unsigned short* __restrict__ hb) {
  const int t    = threadIdx.x;
  const int lane = t & 63;
  const int wave = t >> 6;
  const int wm   = (wave >> 1) * 64;
  const int wn   = (wave & 1) * 64;
  const int m0   = blockIdx.x * 128;
  const int l15  = lane & 15;
  const int quad = lane >> 4;

  facc_t acc[4][4];
#pragma unroll
  for (int i = 0; i < 4; ++i)
#pragma unroll
    for (int j = 0; j < 4; ++j) {
      facc_t z = {0.f, 0.f, 0.f, 0.f};
      acc[i][j] = z;
    }

#pragma unroll
  for (int k0 = 0; k0 < NF; k0 += 32) {
    bfrag_t a[4], b[4];
#pragma unroll
    for (int mi = 0; mi < 4; ++mi) {
      const int m = m0 + wm + mi * 16 + l15;
      a[mi] = *(const bfrag_t*)&xb[(size_t)m * NF + k0 + quad * 8];
    }
#pragma unroll
    for (int ni = 0; ni < 4; ++ni) {
      const int n = wn + ni * 16 + l15;
      b[ni] = *(const bfrag_t*)&Wt[(size_t)n * NF + k0 + quad * 8];
    }
#pragma unroll
    for (int mi = 0; mi < 4; ++mi)
#pragma unroll
      for (int ni = 0; ni < 4; ++ni)
        acc[mi][ni] = __builtin_amdgcn_mfma_f32_16x16x32_bf16(
            a[mi], b[ni], acc[mi][ni], 0, 0, 0);
  }

#pragma unroll
  for (int ni = 0; ni < 4; ++ni) {
    const int n = wn + ni * 16 + l15;
    const float bias = bk[n];
#pragma unroll
    for (int mi = 0; mi < 4; ++mi) {
#pragma unroll
      for (int r = 0; r < 4; ++r) {
        const int m = m0 + wm + mi * 16 + quad * 4 + r;
        if (m < NNODES) hb[(size_t)m * NH + n] = f2bf(acc[mi][ni][r] + bias);
      }
    }
  }
}

// ---------------------------------------------------------------------------
// CSR build step 1: histogram of row ids.
// ---------------------------------------------------------------------------
__global__ __launch_bounds__(256) void hist_kernel(
    const int* __restrict__ rows, int* __restrict__ counts) {
  const int hop = blockIdx.y;
  const int e = blockIdx.x * 256 + threadIdx.x;
  if (e >= NEDGES) return;
  const int r = rows[(size_t)hop * NEDGES + e];
  atomicAdd(&counts[hop * NNODES + r], 1);
}

// ---------------------------------------------------------------------------
// CSR build step 2: exclusive scan per hop (1 block of 1024 per hop).
// ---------------------------------------------------------------------------
__global__ __launch_bounds__(1024) void scan_kernel(
    const int* __restrict__ counts, int* __restrict__ offs,
    int* __restrict__ cursor) {
  const int hop  = blockIdx.x;
  const int t    = threadIdx.x;
  const int lane = t & 63;
  const int wid  = t >> 6;
  __shared__ int wsum[16];
  __shared__ int carry_s;
  if (t == 0) carry_s = 0;
  __syncthreads();
  const int nch = (NNODES + 1023) / 1024;
  for (int ch = 0; ch < nch; ++ch) {
    const int i = ch * 1024 + t;
    int v = (i < NNODES) ? counts[hop * NNODES + i] : 0;
    int s = v;
#pragma unroll
    for (int d = 1; d < 64; d <<= 1) {
      int n = __shfl_up(s, d, 64);
      if (lane >= d) s += n;
    }
    if (lane == 63) wsum[wid] = s;
    __syncthreads();
    if (t < 16) {
      int ws = wsum[t];
#pragma unroll
      for (int d = 1; d < 16; d <<= 1) {
        int n = __shfl_up(ws, d, 16);
        if (t >= d) ws += n;
      }
      wsum[t] = ws;
    }
    __syncthreads();
    const int base = carry_s + (wid ? wsum[wid - 1] : 0);
    const int excl = base + (s - v);
    if (i < NNODES) {
      offs[hop * (NNODES + 1) + i] = excl;
      cursor[hop * NNODES + i]     = excl;
    }
    __syncthreads();
    if (t == 0) carry_s += wsum[15];
    __syncthreads();
  }
  if (t == 0) offs[hop * (NNODES + 1) + NNODES] = carry_s;
}

// ---------------------------------------------------------------------------
// CSR build step 3: scatter (col,val) packed as one int2 (8B store — halves
// the dirtied-line count vs two 4B stores into separate arrays).
// ---------------------------------------------------------------------------
__global__ __launch_bounds__(256) void scatter_kernel(
    const int* __restrict__ rows, const int* __restrict__ cols,
    const float* __restrict__ vals, int* __restrict__ cursor,
    int2* __restrict__ ecsr) {
  const int hop = blockIdx.y;
  const int e = blockIdx.x * 256 + threadIdx.x;
  if (e >= NEDGES) return;
  const size_t g = (size_t)hop * NEDGES + e;
  const int r = rows[g];
  const int pos = atomicAdd(&cursor[hop * NNODES + r], 1);
  ecsr[(size_t)hop * NEDGES + pos] = make_int2(cols[g], __float_as_int(vals[g]));
}

// ---------------------------------------------------------------------------
// Gather SpMM: agg[r][:] = sum_seg val * hb[col][:]  (bf16 in, f32 acc,
// bf16 out). 1 wave per row, 2 feats per lane, no atomics.
// ---------------------------------------------------------------------------
__global__ __launch_bounds__(256) void gather_kernel(
    const int* __restrict__ offs, const int2* __restrict__ ecsr,
    const unsigned short* __restrict__ hb, unsigned short* __restrict__ aggb) {
  const int t    = threadIdx.x;
  const int lane = t & 63;
  const int wid  = t >> 6;
  const int r = blockIdx.x * 4 + wid;
  if (r >= NNODES) return;
  const int s = offs[r];
  const int e = offs[r + 1];
  float ax = 0.f, ay = 0.f;
  int p = s;
  for (; p + 1 < e; p += 2) {
    const int2 e0 = ecsr[p];
    const int2 e1 = ecsr[p + 1];
    const float v0 = __int_as_float(e0.y);
    const float v1 = __int_as_float(e1.y);
    const unsigned int h0 = *(const unsigned int*)&hb[(size_t)e0.x * NH + lane * 2];
    const unsigned int h1 = *(const unsigned int*)&hb[(size_t)e1.x * NH + lane * 2];
    ax += v0 * bf2f_lo(h0) + v1 * bf2f_lo(h1);
    ay += v0 * bf2f_hi(h0) + v1 * bf2f_hi(h1);
  }
  if (p < e) {
    const int2 e0 = ecsr[p];
    const float v0 = __int_as_float(e0.y);
    const unsigned int h0 = *(const unsigned int*)&hb[(size_t)e0.x * NH + lane * 2];
    ax += v0 * bf2f_lo(h0);
    ay += v0 * bf2f_hi(h0);
  }
  ushort2 o;
  o.x = f2bf(ax);
  o.y = f2bf(ay);
  *(ushort2*)&aggb[(size_t)r * NH + lane * 2] = o;
}

// ---------------------------------------------------------------------------
// Output: out[n][o] = b_out[o] + sum_f elu(concat[n][f]) * W_out[f][o]
// ---------------------------------------------------------------------------
__global__ __launch_bounds__(64) void out_kernel(
    const unsigned short* __restrict__ aggb, const float* __restrict__ Wout,
    const float* __restrict__ bout, float* __restrict__ out) {
  __shared__ float zs[16 * 516];
  const int t  = threadIdx.x;
  const int n0 = blockIdx.x * 16;

#pragma unroll
  for (int cch = 0; cch < 32; ++cch) {
    const int flat = cch * 256 + t * 4;
    const int n_l  = flat >> 9;
    const int f    = flat & 511;
    const int k    = f >> 7;
    const int j    = f & 127;
    const uint2 u = *(const uint2*)&aggb[((size_t)k * NNODES + n0 + n_l) * NH + j];
    float4 v = make_float4(bf2f_lo(u.x), bf2f_hi(u.x), bf2f_lo(u.y), bf2f_hi(u.y));
    v.x = v.x > 0.f ? v.x : (expf(v.x) - 1.f);
    v.y = v.y > 0.f ? v.y : (expf(v.y) - 1.f);
    v.z = v.z > 0.f ? v.z : (expf(v.z) - 1.f);
    v.w = v.w > 0.f ? v.w : (expf(v.w) - 1.f);
    *(float4*)&zs[n_l * 516 + f] = v;
  }
  __syncthreads();

  const int og = t & 15;
  const int ng = t >> 4;
  float acc[4][4];
#pragma unroll
  for (int i = 0; i < 4; ++i)
#pragma unroll
    for (int o = 0; o < 4; ++o) acc[i][o] = 0.f;

  for (int fq = 0; fq < 128; ++fq) {
    const int f = fq * 4;
    float4 z[4], w[4];
#pragma unroll
    for (int i = 0; i < 4; ++i)
      z[i] = *(float4*)&zs[(ng * 4 + i) * 516 + f];
#pragma unroll
    for (int u = 0; u < 4; ++u)
      w[u] = *(const float4*)&Wout[(size_t)(f + u) * NO + og * 4];
    float zv[4][4] = {{z[0].x, z[0].y, z[0].z, z[0].w},
                      {z[1].x, z[1].y, z[1].z, z[1].w},
                      {z[2].x, z[2].y, z[2].z, z[2].w},
                      {z[3].x, z[3].y, z[3].z, z[3].w}};
    float wv[4][4] = {{w[0].x, w[0].y, w[0].z, w[0].w},
                      {w[1].x, w[1].y, w[1].z, w[1].w},
                      {w[2].x, w[2].y, w[2].z, w[2].w},
                      {w[3].x, w[3].y, w[3].z, w[3].w}};
#pragma unroll
    for (int i = 0; i < 4; ++i)
#pragma unroll
      for (int u = 0; u < 4; ++u)
#pragma unroll
        for (int o = 0; o < 4; ++o) acc[i][o] += zv[i][u] * wv[u][o];
  }

  float bo[4];
#pragma unroll
  for (int o = 0; o < 4; ++o) bo[o] = bout[og * 4 + o];
#pragma unroll
  for (int i = 0; i < 4; ++i) {
    const int n = n0 + ng * 4 + i;
    float4 r = make_float4(acc[i][0] + bo[0], acc[i][1] + bo[1],
                           acc[i][2] + bo[2], acc[i][3] + bo[3]);
    *(float4*)&out[(size_t)n * NO + og * 4] = r;
  }
}

// ---------------------------------------------------------------------------
extern "C" void kernel_launch(void* const* d_in, const int* in_sizes, int n_in,
                              void* d_out, int out_size, void* d_ws, size_t ws_size,
                              hipStream_t stream) {
  const float* x     = (const float*)d_in[0];
  const float* W     = (const float*)d_in[1];
  const float* b     = (const float*)d_in[2];
  const float* W_out = (const float*)d_in[3];
  const float* b_out = (const float*)d_in[4];
  const int*   erows = (const int*)d_in[5];
  const int*   ecols = (const int*)d_in[6];
  const float* evals = (const float*)d_in[7];
  float* out = (float*)d_out;

  // workspace layout (bytes), total ~118e6 (<128e6 known-safe):
  unsigned short* aggb = (unsigned short*)d_ws;                  // 51.2e6
  unsigned short* xb   = aggb + (size_t)NHOPS * NNODES * NH;     // 25.69e6 (padded rows)
  unsigned short* hb   = xb + (size_t)NPAD * NF;                 // 12.8e6
  unsigned short* Wt   = hb + (size_t)NNODES * NH;               // 0.26e6
  int2* ecsr   = (int2*)(Wt + (size_t)NHOPS * NH * NF);          // 25.6e6
  int*  counts = (int*)(ecsr + (size_t)NHOPS * NEDGES);          // 0.8e6
  int*  offs   = counts + NHOPS * NNODES;                        // 0.8e6
  int*  cursor = offs + NHOPS * (NNODES + 1);                    // 0.8e6

  hipMemsetAsync(counts, 0, (size_t)NHOPS * NNODES * sizeof(int), stream);

  convx_kernel<<<(NNODES * NF / 4 + 255) / 256, 256, 0, stream>>>(x, xb);
  convw_kernel<<<(NHOPS * NH * NF + 255) / 256, 256, 0, stream>>>(W, Wt);

  const dim3 egrid((NEDGES + 255) / 256, NHOPS);
  hist_kernel<<<egrid, 256, 0, stream>>>(erows, counts);
  scan_kernel<<<NHOPS, 1024, 0, stream>>>(counts, offs, cursor);
  scatter_kernel<<<egrid, 256, 0, stream>>>(erows, ecols, evals, cursor, ecsr);

  const int lin_blocks = (NNODES + 127) / 128;   // 391 (rows padded to NPAD)
  for (int k = 0; k < NHOPS; ++k) {
    linear_mfma<<<lin_blocks, 256, 0, stream>>>(
        xb, Wt + (size_t)k * NH * NF, b + (size_t)k * NH, hb);
    gather_kernel<<<(NNODES + 3) / 4, 256, 0, stream>>>(
        offs + (size_t)k * (NNODES + 1), ecsr + (size_t)k * NEDGES, hb,
        aggb + (size_t)k * NNODES * NH);
  }

  out_kernel<<<NNODES / 16, 64, 0, stream>>>(aggb, W_out, b_out, out);
}

// Round 4
// 904.373 us; speedup vs baseline: 6.4789x; 1.0483x over previous
//
#include <hip/hip_runtime.h>
#include <hip/hip_bf16.h>
#include <math.h>

#define NNODES 50000
#define NPAD   50176              // 392*128, padded rows for MFMA tile overrun
#define NEDGES 800000
#define NHOPS  4
#define NF     256
#define NH     128
#define NO     64

#define CONVX_BLOCKS 12500        // NNODES*NF/4/256
#define CONVW_BLOCKS 512          // NHOPS*NH*NF/256
#define HIST_BLOCKS  12500        // (NEDGES/256)*NHOPS
#define LIN_PER_HOP  391          // ceil(NNODES/128)
#define LIN_BLOCKS   (LIN_PER_HOP * NHOPS)     // 1564
#define SCAT_BLOCKS  12500        // (NEDGES/256)*NHOPS

typedef __attribute__((ext_vector_type(8))) short bfrag_t;   // 8 x bf16
typedef __attribute__((ext_vector_type(4))) float facc_t;    // 4 x f32

static __device__ __forceinline__ unsigned short f2bf(float f) {
  unsigned int u = __float_as_uint(f);
  unsigned int r = (u + 0x7fffu + ((u >> 16) & 1u)) >> 16;
  return (unsigned short)r;
}
static __device__ __forceinline__ float bf2f_lo(unsigned int u) {
  return __uint_as_float(u << 16);
}
static __device__ __forceinline__ float bf2f_hi(unsigned int u) {
  return __uint_as_float(u & 0xffff0000u);
}

// ---------------------------------------------------------------------------
// Phase A (fused): convx (x f32 -> bf16) | convw (W -> Wt[k][n][f] bf16) |
// hist (row histogram). All independent.
// ---------------------------------------------------------------------------
__global__ __launch_bounds__(256) void phaseA_kernel(
    const float* __restrict__ x, unsigned short* __restrict__ xb,
    const float* __restrict__ W, unsigned short* __restrict__ Wt,
    const int* __restrict__ erows, int* __restrict__ counts) {
  const int bx = blockIdx.x;
  const int t  = threadIdx.x;
  if (bx < CONVX_BLOCKS) {
    const size_t i = ((size_t)bx * 256 + t) * 4;
    float4 v = *(const float4*)&x[i];
    ushort4 o;
    o.x = f2bf(v.x); o.y = f2bf(v.y); o.z = f2bf(v.z); o.w = f2bf(v.w);
    *(ushort4*)&xb[i] = o;
  } else if (bx < CONVX_BLOCKS + CONVW_BLOCKS) {
    const int i = (bx - CONVX_BLOCKS) * 256 + t;
    const int k = i / (NH * NF);
    const int rem = i - k * NH * NF;
    const int n = rem / NF;
    const int f = rem - n * NF;
    Wt[i] = f2bf(W[(size_t)k * NF * NH + (size_t)f * NH + n]);
  } else {
    const int id  = bx - (CONVX_BLOCKS + CONVW_BLOCKS);
    const int hop = id / 3125;
    const int e   = (id - hop * 3125) * 256 + t;
    const int r = erows[(size_t)hop * NEDGES + e];
    atomicAdd(&counts[hop * NNODES + r], 1);
  }
}

// ---------------------------------------------------------------------------
// CSR build step 2: exclusive scan per hop (1 block of 1024 per hop).
// ---------------------------------------------------------------------------
__global__ __launch_bounds__(1024) void scan_kernel(
    const int* __restrict__ counts, int* __restrict__ offs,
    int* __restrict__ cursor) {
  const int hop  = blockIdx.x;
  const int t    = threadIdx.x;
  const int lane = t & 63;
  const int wid  = t >> 6;
  __shared__ int wsum[16];
  __shared__ int carry_s;
  if (t == 0) carry_s = 0;
  __syncthreads();
  const int nch = (NNODES + 1023) / 1024;
  for (int ch = 0; ch < nch; ++ch) {
    const int i = ch * 1024 + t;
    int v = (i < NNODES) ? counts[hop * NNODES + i] : 0;
    int s = v;
#pragma unroll
    for (int d = 1; d < 64; d <<= 1) {
      int n = __shfl_up(s, d, 64);
      if (lane >= d) s += n;
    }
    if (lane == 63) wsum[wid] = s;
    __syncthreads();
    if (t < 16) {
      int ws = wsum[t];
#pragma unroll
      for (int d = 1; d < 16; d <<= 1) {
        int n = __shfl_up(ws, d, 16);
        if (t >= d) ws += n;
      }
      wsum[t] = ws;
    }
    __syncthreads();
    const int base = carry_s + (wid ? wsum[wid - 1] : 0);
    const int excl = base + (s - v);
    if (i < NNODES) {
      offs[hop * (NNODES + 1) + i] = excl;
      cursor[hop * NNODES + i]     = excl;
    }
    __syncthreads();
    if (t == 0) carry_s += wsum[15];
    __syncthreads();
  }
  if (t == 0) offs[hop * (NNODES + 1) + NNODES] = carry_s;
}

// ---------------------------------------------------------------------------
// Phase C (fused): linear x4 hops (MFMA, no LDS) || scatter (CSR edge fill,
// nontemporal 8B stores — no L2 line churn). Independent halves.
// slots: hb[k] = slots + (k+1)*NNODES*NH; agg[k] = slots + k*NNODES*NH.
// ---------------------------------------------------------------------------
__global__ __launch_bounds__(256) void phaseC_kernel(
    const unsigned short* __restrict__ xb, const unsigned short* __restrict__ Wt,
    const float* __restrict__ b, unsigned short* __restrict__ slots,
    const int* __restrict__ erows, const int* __restrict__ ecols,
    const float* __restrict__ evals, int* __restrict__ cursor,
    unsigned long long* __restrict__ ecsr) {
  const int bx = blockIdx.x;
  const int t  = threadIdx.x;
  if (bx < LIN_BLOCKS) {
    // ---- linear via MFMA ----
    const int hop = bx / LIN_PER_HOP;
    const int mb  = bx - hop * LIN_PER_HOP;
    const unsigned short* Wk = Wt + (size_t)hop * NH * NF;
    const float* bk = b + hop * NH;
    unsigned short* hb = slots + (size_t)(hop + 1) * NNODES * NH;

    const int lane = t & 63;
    const int wave = t >> 6;
    const int wm   = (wave >> 1) * 64;
    const int wn   = (wave & 1) * 64;
    const int m0   = mb * 128;
    const int l15  = lane & 15;
    const int quad = lane >> 4;

    facc_t acc[4][4];
#pragma unroll
    for (int i = 0; i < 4; ++i)
#pragma unroll
      for (int j = 0; j < 4; ++j) {
        facc_t z = {0.f, 0.f, 0.f, 0.f};
        acc[i][j] = z;
      }

#pragma unroll
    for (int k0 = 0; k0 < NF; k0 += 32) {
      bfrag_t a[4], bb[4];
#pragma unroll
      for (int mi = 0; mi < 4; ++mi) {
        const int m = m0 + wm + mi * 16 + l15;
        a[mi] = *(const bfrag_t*)&xb[(size_t)m * NF + k0 + quad * 8];
      }
#pragma unroll
      for (int ni = 0; ni < 4; ++ni) {
        const int n = wn + ni * 16 + l15;
        bb[ni] = *(const bfrag_t*)&Wk[(size_t)n * NF + k0 + quad * 8];
      }
#pragma unroll
      for (int mi = 0; mi < 4; ++mi)
#pragma unroll
        for (int ni = 0; ni < 4; ++ni)
          acc[mi][ni] = __builtin_amdgcn_mfma_f32_16x16x32_bf16(
              a[mi], bb[ni], acc[mi][ni], 0, 0, 0);
    }

#pragma unroll
    for (int ni = 0; ni < 4; ++ni) {
      const int n = wn + ni * 16 + l15;
      const float bias = bk[n];
#pragma unroll
      for (int mi = 0; mi < 4; ++mi) {
#pragma unroll
        for (int r = 0; r < 4; ++r) {
          const int m = m0 + wm + mi * 16 + quad * 4 + r;
          if (m < NNODES) hb[(size_t)m * NH + n] = f2bf(acc[mi][ni][r] + bias);
        }
      }
    }
  } else {
    // ---- scatter ----
    const int id  = bx - LIN_BLOCKS;
    const int hop = id / 3125;
    const int e   = (id - hop * 3125) * 256 + t;
    const size_t g = (size_t)hop * NEDGES + e;
    const int r = erows[g];
    const int pos = atomicAdd(&cursor[hop * NNODES + r], 1);
    const unsigned long long pk =
        ((unsigned long long)__float_as_uint(evals[g]) << 32) |
        (unsigned int)ecols[g];
    __builtin_nontemporal_store(pk, &ecsr[(size_t)hop * NEDGES + pos]);
  }
}

// ---------------------------------------------------------------------------
// Gather SpMM: agg[r][:] = sum_seg val * hb[col][:].
// 4 rows/block (1 wave/row); wave = 4 edge-groups x 16 lanes x 16B loads;
// 8 edges in flight per iteration; xor-shuffle reduction across groups.
// ---------------------------------------------------------------------------
__global__ __launch_bounds__(256) void gather_kernel(
    const int* __restrict__ offs, const int2* __restrict__ ecsr,
    const unsigned short* __restrict__ hb, unsigned short* __restrict__ aggb) {
  const int t    = threadIdx.x;
  const int lane = t & 63;
  const int wid  = t >> 6;
  const int r = blockIdx.x * 4 + wid;
  const int g  = lane >> 4;    // edge subgroup 0..3
  const int sl = lane & 15;    // feature slice: feats sl*8 .. sl*8+7
  const int s = offs[r];
  const int e = offs[r + 1];

  float acc[8];
#pragma unroll
  for (int j = 0; j < 8; ++j) acc[j] = 0.f;

  for (int p = s; p < e; p += 8) {
    const int i0 = p + g;
    const int i1 = p + 4 + g;
    int2 e0 = (i0 < e) ? ecsr[i0] : make_int2(0, 0);
    int2 e1 = (i1 < e) ? ecsr[i1] : make_int2(0, 0);
    const float v0 = __int_as_float(e0.y);
    const float v1 = __int_as_float(e1.y);
    const uint4 h0 = *(const uint4*)&hb[(size_t)e0.x * NH + sl * 8];
    const uint4 h1 = *(const uint4*)&hb[(size_t)e1.x * NH + sl * 8];
    acc[0] += v0 * bf2f_lo(h0.x) + v1 * bf2f_lo(h1.x);
    acc[1] += v0 * bf2f_hi(h0.x) + v1 * bf2f_hi(h1.x);
    acc[2] += v0 * bf2f_lo(h0.y) + v1 * bf2f_lo(h1.y);
    acc[3] += v0 * bf2f_hi(h0.y) + v1 * bf2f_hi(h1.y);
    acc[4] += v0 * bf2f_lo(h0.z) + v1 * bf2f_lo(h1.z);
    acc[5] += v0 * bf2f_hi(h0.z) + v1 * bf2f_hi(h1.z);
    acc[6] += v0 * bf2f_lo(h0.w) + v1 * bf2f_lo(h1.w);
    acc[7] += v0 * bf2f_hi(h0.w) + v1 * bf2f_hi(h1.w);
  }

#pragma unroll
  for (int j = 0; j < 8; ++j) {
    acc[j] += __shfl_xor(acc[j], 16, 64);
    acc[j] += __shfl_xor(acc[j], 32, 64);
  }

  if (g == 0) {
    uint4 o;
    o.x = (unsigned)f2bf(acc[0]) | ((unsigned)f2bf(acc[1]) << 16);
    o.y = (unsigned)f2bf(acc[2]) | ((unsigned)f2bf(acc[3]) << 16);
    o.z = (unsigned)f2bf(acc[4]) | ((unsigned)f2bf(acc[5]) << 16);
    o.w = (unsigned)f2bf(acc[6]) | ((unsigned)f2bf(acc[7]) << 16);
    *(uint4*)&aggb[(size_t)r * NH + sl * 8] = o;
  }
}

// ---------------------------------------------------------------------------
// Output: out[n][o] = b_out[o] + sum_f elu(concat[n][f]) * W_out[f][o]
// ---------------------------------------------------------------------------
__global__ __launch_bounds__(64) void out_kernel(
    const unsigned short* __restrict__ aggb, const float* __restrict__ Wout,
    const float* __restrict__ bout, float* __restrict__ out) {
  __shared__ float zs[16 * 516];
  const int t  = threadIdx.x;
  const int n0 = blockIdx.x * 16;

#pragma unroll
  for (int cch = 0; cch < 32; ++cch) {
    const int flat = cch * 256 + t * 4;
    const int n_l  = flat >> 9;
    const int f    = flat & 511;
    const int k    = f >> 7;
    const int j    = f & 127;
    const uint2 u = *(const uint2*)&aggb[((size_t)k * NNODES + n0 + n_l) * NH + j];
    float4 v = make_float4(bf2f_lo(u.x), bf2f_hi(u.x), bf2f_lo(u.y), bf2f_hi(u.y));
    v.x = v.x > 0.f ? v.x : (expf(v.x) - 1.f);
    v.y = v.y > 0.f ? v.y : (expf(v.y) - 1.f);
    v.z = v.z > 0.f ? v.z : (expf(v.z) - 1.f);
    v.w = v.w > 0.f ? v.w : (expf(v.w) - 1.f);
    *(float4*)&zs[n_l * 516 + f] = v;
  }
  __syncthreads();

  const int og = t & 15;
  const int ng = t >> 4;
  float acc[4][4];
#pragma unroll
  for (int i = 0; i < 4; ++i)
#pragma unroll
    for (int o = 0; o < 4; ++o) acc[i][o] = 0.f;

  for (int fq = 0; fq < 128; ++fq) {
    const int f = fq * 4;
    float4 z[4], w[4];
#pragma unroll
    for (int i = 0; i < 4; ++i)
      z[i] = *(float4*)&zs[(ng * 4 + i) * 516 + f];
#pragma unroll
    for (int u = 0; u < 4; ++u)
      w[u] = *(const float4*)&Wout[(size_t)(f + u) * NO + og * 4];
    float zv[4][4] = {{z[0].x, z[0].y, z[0].z, z[0].w},
                      {z[1].x, z[1].y, z[1].z, z[1].w},
                      {z[2].x, z[2].y, z[2].z, z[2].w},
                      {z[3].x, z[3].y, z[3].z, z[3].w}};
    float wv[4][4] = {{w[0].x, w[0].y, w[0].z, w[0].w},
                      {w[1].x, w[1].y, w[1].z, w[1].w},
                      {w[2].x, w[2].y, w[2].z, w[2].w},
                      {w[3].x, w[3].y, w[3].z, w[3].w}};
#pragma unroll
    for (int i = 0; i < 4; ++i)
#pragma unroll
      for (int u = 0; u < 4; ++u)
#pragma unroll
        for (int o = 0; o < 4; ++o) acc[i][o] += zv[i][u] * wv[u][o];
  }

  float bo[4];
#pragma unroll
  for (int o = 0; o < 4; ++o) bo[o] = bout[og * 4 + o];
#pragma unroll
  for (int i = 0; i < 4; ++i) {
    const int n = n0 + ng * 4 + i;
    float4 r = make_float4(acc[i][0] + bo[0], acc[i][1] + bo[1],
                           acc[i][2] + bo[2], acc[i][3] + bo[3]);
    *(float4*)&out[(size_t)n * NO + og * 4] = r;
  }
}

// ---------------------------------------------------------------------------
extern "C" void kernel_launch(void* const* d_in, const int* in_sizes, int n_in,
                              void* d_out, int out_size, void* d_ws, size_t ws_size,
                              hipStream_t stream) {
  const float* x     = (const float*)d_in[0];
  const float* W     = (const float*)d_in[1];
  const float* b     = (const float*)d_in[2];
  const float* W_out = (const float*)d_in[3];
  const float* b_out = (const float*)d_in[4];
  const int*   erows = (const int*)d_in[5];
  const int*   ecols = (const int*)d_in[6];
  const float* evals = (const float*)d_in[7];
  float* out = (float*)d_out;

  // ws layout (bytes), total ~118e6 (<128e6 known-safe):
  //   slots: 5 x NNODES*NH bf16 = 64.0e6   (agg[k]=slot k, hb[k]=slot k+1;
  //          agg[k] aliases hb[k-1], which is dead after gather_{k-1})
  //   xb: NPAD*NF bf16 = 25.7e6
  //   Wt: 4*NH*NF bf16 = 0.26e6
  //   ecsr: 4*NEDGES*8 = 25.6e6
  //   counts/offs/cursor ints = 2.4e6
  unsigned short* slots = (unsigned short*)d_ws;
  unsigned short* xb = slots + (size_t)(NHOPS + 1) * NNODES * NH;
  unsigned short* Wt = xb + (size_t)NPAD * NF;
  unsigned long long* ecsr = (unsigned long long*)(Wt + (size_t)NHOPS * NH * NF);
  int* counts = (int*)(ecsr + (size_t)NHOPS * NEDGES);
  int* offs   = counts + NHOPS * NNODES;
  int* cursor = offs + NHOPS * (NNODES + 1);

  hipMemsetAsync(counts, 0, (size_t)NHOPS * NNODES * sizeof(int), stream);

  phaseA_kernel<<<CONVX_BLOCKS + CONVW_BLOCKS + HIST_BLOCKS, 256, 0, stream>>>(
      x, xb, W, Wt, erows, counts);
  scan_kernel<<<NHOPS, 1024, 0, stream>>>(counts, offs, cursor);
  phaseC_kernel<<<LIN_BLOCKS + SCAT_BLOCKS, 256, 0, stream>>>(
      xb, Wt, b, slots, erows, ecols, evals, cursor, ecsr);

  for (int k = 0; k < NHOPS; ++k) {
    gather_kernel<<<NNODES / 4, 256, 0, stream>>>(
        offs + (size_t)k * (NNODES + 1), (const int2*)(ecsr + (size_t)k * NEDGES),
        slots + (size_t)(k + 1) * NNODES * NH,   // hb[k]
        slots + (size_t)k * NNODES * NH);        // agg[k]
  }

  out_kernel<<<NNODES / 16, 64, 0, stream>>>(slots, W_out, b_out, out);
}